// Round 1
// baseline (138.648 us; speedup 1.0000x reference)
//
#include <hip/hip_runtime.h>

// QNN: 8 qubits, 2 layers (8 RY + 7-CNOT chain each), measure first 5 qubits.
// One wave64 per batch element; state = 256 f32, 4 per lane.
//   idx = lane*4 + r   (lane = bits 7..2, r = bits 1..0)
// CNOT chain c=0..6  ==  binary-to-Gray permutation: after[idx]=before[idx^(idx>>1)].
//   -> layer-1 (product state) evaluated directly at Gray-permuted index,
//   -> layer-2 chain folded into measurement group m = gray2bin5(lane>>1).

constexpr int F = 16;

__global__ __launch_bounds__(256) void qnn_kernel(
    const float* __restrict__ inputs,
    const float* __restrict__ weights,
    const float* __restrict__ scalings,
    float* __restrict__ out, int B)
{
    const int gtid = blockIdx.x * 256 + threadIdx.x;
    const int b    = gtid >> 6;          // one wave per batch element
    const int lane = threadIdx.x & 63;
    if (b >= B) return;

    // ---- angles: lane k<16 owns (layer k>>3, wire k&7); all lanes compute
    const int li = lane & 15;
    const float x     = inputs[(size_t)b * F + li];
    const float theta = weights[li] + scalings[li] * x;
    float sv, cv;
    __sincosf(0.5f * theta, &sv, &cv);

    // broadcast layer-0 cos/sin (lanes 0..7) -> readlane, cheap
    float c0[8], s0[8], c1[8], s1[8];
    #pragma unroll
    for (int w = 0; w < 8; ++w) {
        c0[w] = __shfl(cv, w);      s0[w] = __shfl(sv, w);
        c1[w] = __shfl(cv, 8 + w);  s1[w] = __shfl(sv, 8 + w);
    }

    // ---- layer 1: product state at Gray-permuted index g = idx ^ (idx>>1)
    // g bits 7..2 are common to the lane's 4 elements: gl = lane ^ (lane>>1)
    const int gl = lane ^ (lane >> 1);   // gl bit j == g bit (j+2)
    float prod_hi = 1.0f;
    #pragma unroll
    for (int w = 0; w < 6; ++w) {        // wire w selected by g bit (7-w)
        prod_hi *= ((gl >> (5 - w)) & 1) ? s0[w] : c0[w];
    }
    // wire 6 selected by g1 = r1 ^ lane0 ; wire 7 by g0 = r0 ^ r1
    const bool lb0 = (lane & 1);
    const float A  = prod_hi * (lb0 ? s0[6] : c0[6]);   // r = 0,1
    const float Bm = prod_hi * (lb0 ? c0[6] : s0[6]);   // r = 2,3
    float v[4];
    v[0] = A  * c0[7];
    v[1] = A  * s0[7];
    v[2] = Bm * s0[7];
    v[3] = Bm * c0[7];

    // ---- layer 2 RYs on the entangled state
    // wires 0..5: partner across lanes (bit 7-w -> lane bit 5-w)
    #pragma unroll
    for (int w = 0; w < 6; ++w) {
        const int mask = 1 << (5 - w);
        const float u0 = __shfl_xor(v[0], mask);
        const float u1 = __shfl_xor(v[1], mask);
        const float u2 = __shfl_xor(v[2], mask);
        const float u3 = __shfl_xor(v[3], mask);
        const bool side = (lane >> (5 - w)) & 1;   // 0: a0' = c*a0 - s*a1 ; 1: a1' = c*a1 + s*a0
        const float ss = side ? s1[w] : -s1[w];
        v[0] = fmaf(c1[w], v[0], ss * u0);
        v[1] = fmaf(c1[w], v[1], ss * u1);
        v[2] = fmaf(c1[w], v[2], ss * u2);
        v[3] = fmaf(c1[w], v[3], ss * u3);
    }
    // wire 6: bit1 -> pairs (v0,v2),(v1,v3) in-register
    {
        const float c = c1[6], s = s1[6];
        const float n0 = fmaf(c, v[0], -s * v[2]);
        const float n2 = fmaf(c, v[2],  s * v[0]);
        const float n1 = fmaf(c, v[1], -s * v[3]);
        const float n3 = fmaf(c, v[3],  s * v[1]);
        v[0] = n0; v[1] = n1; v[2] = n2; v[3] = n3;
    }
    // wire 7: bit0 -> pairs (v0,v1),(v2,v3)
    {
        const float c = c1[7], s = s1[7];
        const float n0 = fmaf(c, v[0], -s * v[1]);
        const float n1 = fmaf(c, v[1],  s * v[0]);
        const float n2 = fmaf(c, v[2], -s * v[3]);
        const float n3 = fmaf(c, v[3],  s * v[2]);
        v[0] = n0; v[1] = n1; v[2] = n2; v[3] = n3;
    }

    // ---- measurement: layer-2 CNOT chain folded into group index.
    // All 4 elements of a lane (and its odd neighbor) land in group
    // m = gray2bin(lane>>1) over 5 bits.
    float ssum = v[0] * v[0];
    ssum = fmaf(v[1], v[1], ssum);
    ssum = fmaf(v[2], v[2], ssum);
    ssum = fmaf(v[3], v[3], ssum);
    ssum += __shfl_xor(ssum, 1);

    int m = lane >> 1;
    m ^= m >> 1; m ^= m >> 2; m ^= m >> 4;   // 5-bit gray -> binary (prefix xor)

    if (!(lane & 1)) out[(size_t)b * 32 + m] = ssum;
}

extern "C" void kernel_launch(void* const* d_in, const int* in_sizes, int n_in,
                              void* d_out, int out_size, void* d_ws, size_t ws_size,
                              hipStream_t stream) {
    const float* inputs   = (const float*)d_in[0];
    const float* weights  = (const float*)d_in[1];
    const float* scalings = (const float*)d_in[2];
    float* out = (float*)d_out;
    const int B = in_sizes[0] / F;          // 131072
    const int waves_per_block = 4;          // 256 threads
    const int grid = (B + waves_per_block - 1) / waves_per_block;
    qnn_kernel<<<grid, 256, 0, stream>>>(inputs, weights, scalings, out, B);
}

// Round 2
// 70.377 us; speedup vs baseline: 1.9701x; 1.9701x over previous
//
#include <hip/hip_runtime.h>

// QNN as a bond-dim-2 MPS, squared -> symmetric bond-dim-3 transfer chain.
// One THREAD per batch element (was: one wave64/element).
//
// amp2[z] = l . A_0(z0) ... A_7(z7) . 1,  A_w(z)[a,y] = M_w(z,y) t_w(y^a)
//   t_w = (cos h1_w, sin h1_w) ; M_w = [[c2,-s2],[s2,c2]] (h = theta/2)
// p(G) = sum_{z5,z6,z7} |amp2|^2,  G = gray_decode(Z), Z = z0..z4 (MSB..).
// Squared chain in symmetric rep V=(P,Q,R) ([[P,Q],[Q,R]]):
//   measured site (entries u=c2^2,v=s2^2,t=c2s2, p=c1^2,q=s1^2,r=c1s1):
//     z=0: P'=up*P - 2tr*Q + vq*R ; Q'=ur*P - t*Q + vr*R ; R'=uq*P - 2tr*Q + vp*R
//     z=1: P'=vp*P + 2tr*Q + uq*R ; Q'=vr*P + t*Q + ur*R ; R'=vq*P + 2tr*Q + up*R
//   traced site (sum over z): P'=p*P+q*R ; Q'=r*(P+R) ; R'=q*P+p*R
//     -> from V=1: right env after tracing qubits 5,6,7 is (1, sin(theta1_5), 1).

constexpr int F = 16;

struct Sym { float P, Q, R; };
struct Ent { float up, uq, ur, vp, vq, vr, t, tr2; };

__device__ __forceinline__ Ent mk_ent(float c1, float s1, float c2, float s2) {
    const float u = c2 * c2, v = s2 * s2, t = c2 * s2;
    const float p = c1 * c1, q = s1 * s1, r = c1 * s1;
    Ent e;
    e.up = u * p; e.uq = u * q; e.ur = u * r;
    e.vp = v * p; e.vq = v * q; e.vr = v * r;
    e.t  = t;     e.tr2 = 2.0f * t * r;
    return e;
}

template <int Z>
__device__ __forceinline__ Sym apply_z(const Ent& e, const Sym& s) {
    if (Z == 0) {
        return Sym{ fmaf(e.up, s.P, fmaf(-e.tr2, s.Q, e.vq * s.R)),
                    fmaf(e.ur, s.P, fmaf(-e.t,   s.Q, e.vr * s.R)),
                    fmaf(e.uq, s.P, fmaf(-e.tr2, s.Q, e.vp * s.R)) };
    } else {
        return Sym{ fmaf(e.vp, s.P, fmaf( e.tr2, s.Q, e.uq * s.R)),
                    fmaf(e.vr, s.P, fmaf( e.t,   s.Q, e.ur * s.R)),
                    fmaf(e.vq, s.P, fmaf( e.tr2, s.Q, e.up * s.R)) };
    }
}

__global__ __launch_bounds__(256) void qnn_mps_kernel(
    const float* __restrict__ inputs,
    const float* __restrict__ weights,
    const float* __restrict__ scalings,
    float* __restrict__ out, int B)
{
    const int b = blockIdx.x * 256 + threadIdx.x;
    if (b >= B) return;

    // ---- load this element's 16 features (4x float4, 64B-aligned)
    const float4* in4 = reinterpret_cast<const float4*>(inputs) + (size_t)b * 4;
    const float4 xa = in4[0], xb = in4[1], xc = in4[2], xd = in4[3];
    const float x[16] = { xa.x, xa.y, xa.z, xa.w,  xb.x, xb.y, xb.z, xb.w,
                          xc.x, xc.y, xc.z, xc.w,  xd.x, xd.y, xd.z, xd.w };

    // ---- angles: layer1 wires 0..4 (k=w), layer2 wires 0..4 (k=8+w),
    //      plus full-angle sin for layer1 wire 5. Wires 6,7 drop out.
    float c1[5], s1[5], c2[5], s2[5];
    #pragma unroll
    for (int w = 0; w < 5; ++w) {
        const float t1 = weights[w]     + scalings[w]     * x[w];
        const float t2 = weights[8 + w] + scalings[8 + w] * x[8 + w];
        __sincosf(0.5f * t1, &s1[w], &c1[w]);
        __sincosf(0.5f * t2, &s2[w], &c2[w]);
    }
    const float th5 = weights[5] + scalings[5] * x[5];
    const float s5  = __sinf(th5);

    // ---- right environment over traced qubits 5,6,7
    const Sym r5{ 1.0f, s5, 1.0f };

    // ---- tree over measured qubits 4..1 (BFS from the right)
    const Ent e4 = mk_ent(c1[4], s1[4], c2[4], s2[4]);
    Sym r4[2];
    r4[0] = apply_z<0>(e4, r5);
    r4[1] = apply_z<1>(e4, r5);

    const Ent e3 = mk_ent(c1[3], s1[3], c2[3], s2[3]);
    Sym r3[4];
    r3[0] = apply_z<0>(e3, r4[0]);  r3[1] = apply_z<0>(e3, r4[1]);
    r3[2] = apply_z<1>(e3, r4[0]);  r3[3] = apply_z<1>(e3, r4[1]);

    const Ent e2 = mk_ent(c1[2], s1[2], c2[2], s2[2]);
    Sym r2[8];
    #pragma unroll
    for (int j = 0; j < 4; ++j) {
        r2[j]     = apply_z<0>(e2, r3[j]);
        r2[4 + j] = apply_z<1>(e2, r3[j]);
    }

    const Ent e1 = mk_ent(c1[1], s1[1], c2[1], s2[1]);
    const Ent e0 = mk_ent(c1[0], s1[0], c2[0], s2[0]);

    float pr[32];
    #pragma unroll
    for (int j = 0; j < 8; ++j) {        // j = (z2<<2)|(z3<<1)|z4
        #pragma unroll
        for (int z1 = 0; z1 < 2; ++z1) {
            const Sym v = (z1 == 0) ? apply_z<0>(e1, r2[j]) : apply_z<1>(e1, r2[j]);
            #pragma unroll
            for (int z0 = 0; z0 < 2; ++z0) {
                const float p = (z0 == 0)
                    ? fmaf(e0.up, v.P, fmaf(-e0.tr2, v.Q, e0.vq * v.R))
                    : fmaf(e0.vp, v.P, fmaf( e0.tr2, v.Q, e0.uq * v.R));
                const int Z = (z0 << 4) | (z1 << 3) | j;
                int G = Z; G ^= G >> 1; G ^= G >> 2; G ^= G >> 4;  // gray->bin
                pr[G & 31] = p;          // compile-time index after unroll
            }
        }
    }

    // ---- 128B contiguous output per thread: 8x float4
    float4* o4 = reinterpret_cast<float4*>(out) + (size_t)b * 8;
    #pragma unroll
    for (int i = 0; i < 8; ++i)
        o4[i] = make_float4(pr[4 * i], pr[4 * i + 1], pr[4 * i + 2], pr[4 * i + 3]);
}

extern "C" void kernel_launch(void* const* d_in, const int* in_sizes, int n_in,
                              void* d_out, int out_size, void* d_ws, size_t ws_size,
                              hipStream_t stream) {
    const float* inputs   = (const float*)d_in[0];
    const float* weights  = (const float*)d_in[1];
    const float* scalings = (const float*)d_in[2];
    float* out = (float*)d_out;
    const int B = in_sizes[0] / F;                 // 131072
    const int grid = (B + 255) / 256;              // 512 blocks
    qnn_mps_kernel<<<grid, 256, 0, stream>>>(inputs, weights, scalings, out, B);
}

// Round 3
// 68.573 us; speedup vs baseline: 2.0219x; 1.0263x over previous
//
#include <hip/hip_runtime.h>

// QNN as a squared bond-dim-2 MPS -> symmetric bond-dim-3 transfer chain.
// Round 3: FOUR threads per batch element (t = gtid&3 carries measured bits
// z0,z1), 524288 threads = 8192 waves = 8/SIMD for latency hiding
// (round 2 had only 2 waves/SIMD and was latency/ramp-bound at ~18us).
//
// Mapping (verified against the passing round-2 kernel):
//   output index G = 8*t + u (u=0..7, contiguous 32B per thread)
//   Z = G ^ (G>>1)  (bin->gray);  z0 = t>>1, z1 = (t&1)^(t>>1)  [t-only]
//   j = Z&7 = grayu ^ ((t&1)<<2), grayu = u^(u>>1)  -> fold (t&1) into r2
//   storage order so all array indices are compile-time (no scratch).
// Runtime z-bits enter via cndmask-selected "effective" gate coefficients.

constexpr int F = 16;

struct Sym { float P, Q, R; };
struct Ent { float up, uq, ur, vp, vq, vr, t, tr2; };
struct Eff { float A, B, C, D, E, Fc, G, H; };   // z-resolved gate

__device__ __forceinline__ Ent mk_ent(float c1, float s1, float c2, float s2) {
    const float u = c2 * c2, v = s2 * s2, t = c2 * s2;
    const float p = c1 * c1, q = s1 * s1, r = c1 * s1;
    Ent e;
    e.up = u * p; e.uq = u * q; e.ur = u * r;
    e.vp = v * p; e.vq = v * q; e.vr = v * r;
    e.t  = t;     e.tr2 = 2.0f * t * r;
    return e;
}

// z=0: P'=up P -tr2 Q +vq R ; Q'=ur P -t Q +vr R ; R'=uq P -tr2 Q +vp R
// z=1: P'=vp P +tr2 Q +uq R ; Q'=vr P +t Q +ur R ; R'=vq P +tr2 Q +up R
template <int Z>
__device__ __forceinline__ Sym apply_z(const Ent& e, const Sym& s) {
    if (Z == 0) {
        return Sym{ fmaf(e.up, s.P, fmaf(-e.tr2, s.Q, e.vq * s.R)),
                    fmaf(e.ur, s.P, fmaf(-e.t,   s.Q, e.vr * s.R)),
                    fmaf(e.uq, s.P, fmaf(-e.tr2, s.Q, e.vp * s.R)) };
    } else {
        return Sym{ fmaf(e.vp, s.P, fmaf( e.tr2, s.Q, e.uq * s.R)),
                    fmaf(e.vr, s.P, fmaf( e.t,   s.Q, e.ur * s.R)),
                    fmaf(e.vq, s.P, fmaf( e.tr2, s.Q, e.up * s.R)) };
    }
}

__device__ __forceinline__ Eff mk_eff(const Ent& e, bool z) {
    Eff f;
    f.A = z ? e.vp  :  e.up;   f.B = z ? e.tr2 : -e.tr2;
    f.C = z ? e.uq  :  e.vq;   f.D = z ? e.vr  :  e.ur;
    f.E = z ? e.t   : -e.t;    f.Fc= z ? e.ur  :  e.vr;
    f.G = z ? e.vq  :  e.uq;   f.H = z ? e.up  :  e.vp;
    return f;
}
// opposite-z variant = permutation + sign flips (no extra selects)
__device__ __forceinline__ Eff flip_eff(const Eff& e) {
    return Eff{ e.H, -e.B, e.G, e.Fc, -e.E, e.D, e.C, e.A };
}
__device__ __forceinline__ Sym apply_eff(const Eff& e, const Sym& s) {
    return Sym{ fmaf(e.A, s.P, fmaf(e.B, s.Q, e.C  * s.R)),
                fmaf(e.D, s.P, fmaf(e.E, s.Q, e.Fc * s.R)),
                fmaf(e.G, s.P, fmaf(e.B, s.Q, e.H  * s.R)) };
}

__global__ __launch_bounds__(256) void qnn_mps4_kernel(
    const float* __restrict__ inputs,
    const float* __restrict__ weights,
    const float* __restrict__ scalings,
    float* __restrict__ out, int B)
{
    const int g = blockIdx.x * 256 + threadIdx.x;
    const int b = g >> 2;                 // batch element
    const int t = g & 3;                  // output slice / measured bits
    if (b >= B) return;

    const bool z0 = (t >> 1) & 1;
    const bool z1 = ((t ^ (t >> 1)) & 1);
    const bool tb = (t & 1);              // folded into r2 order (z2 bit)

    // ---- features (coalesced; 4 lanes of an element share cachelines)
    const float4* in4 = reinterpret_cast<const float4*>(inputs) + (size_t)b * 4;
    const float4 xa = in4[0], xb = in4[1], xc = in4[2], xd = in4[3];
    const float x[16] = { xa.x, xa.y, xa.z, xa.w,  xb.x, xb.y, xb.z, xb.w,
                          xc.x, xc.y, xc.z, xc.w,  xd.x, xd.y, xd.z, xd.w };

    // ---- angles: layer1 wires 0..4 (half), layer2 wires 0..4 (half),
    //      layer1 wire5 full-angle sin. Wires 6,7 trace out.
    float c1[5], s1[5], c2[5], s2[5];
    #pragma unroll
    for (int w = 0; w < 5; ++w) {
        const float t1 = weights[w]     + scalings[w]     * x[w];
        const float t2 = weights[8 + w] + scalings[8 + w] * x[8 + w];
        __sincosf(0.5f * t1, &s1[w], &c1[w]);
        __sincosf(0.5f * t2, &s2[w], &c2[w]);
    }
    const float th5 = weights[5] + scalings[5] * x[5];
    const float s5  = __sinf(th5);

    // ---- right environment after tracing qubits 5,6,7
    const Sym r5{ 1.0f, s5, 1.0f };

    // ---- full tree for qubits 4,3 (compile-time z)
    const Ent e4 = mk_ent(c1[4], s1[4], c2[4], s2[4]);
    Sym r4[2];
    r4[0] = apply_z<0>(e4, r5);
    r4[1] = apply_z<1>(e4, r5);

    const Ent e3 = mk_ent(c1[3], s1[3], c2[3], s2[3]);
    Sym r3[4];                             // index = (z3<<1)|z4
    r3[0] = apply_z<0>(e3, r4[0]);  r3[1] = apply_z<0>(e3, r4[1]);
    r3[2] = apply_z<1>(e3, r4[0]);  r3[3] = apply_z<1>(e3, r4[1]);

    // ---- qubit 2: both variants, stored in t-folded order
    // r2p[j'] = r2[j' ^ (tb<<2)]
    const Ent e2 = mk_ent(c1[2], s1[2], c2[2], s2[2]);
    const Eff e2a = mk_eff(e2, tb);        // z2 = tb
    const Eff e2b = flip_eff(e2a);         // z2 = !tb
    Sym r2p[8];
    #pragma unroll
    for (int j = 0; j < 4; ++j) {
        r2p[j]     = apply_eff(e2a, r3[j]);
        r2p[4 + j] = apply_eff(e2b, r3[j]);
    }

    // ---- qubits 1,0: thread-fixed z1,z0
    const Eff e1e = mk_eff(mk_ent(c1[1], s1[1], c2[1], s2[1]), z1);
    const Ent e0  = mk_ent(c1[0], s1[0], c2[0], s2[0]);
    const float A0 = z0 ? e0.vp  :  e0.up;
    const float B0 = z0 ? e0.tr2 : -e0.tr2;
    const float C0 = z0 ? e0.uq  :  e0.vq;

    float pr[8];
    #pragma unroll
    for (int u = 0; u < 8; ++u) {
        constexpr int gray[8] = {0, 1, 3, 2, 6, 7, 5, 4};
        const Sym v = apply_eff(e1e, r2p[gray[u]]);
        pr[u] = fmaf(A0, v.P, fmaf(B0, v.Q, C0 * v.R));
    }

    // ---- contiguous 32B store per thread: out[b*32 + 8t .. +7]
    float4* o4 = reinterpret_cast<float4*>(out) + (size_t)b * 8 + (size_t)t * 2;
    o4[0] = make_float4(pr[0], pr[1], pr[2], pr[3]);
    o4[1] = make_float4(pr[4], pr[5], pr[6], pr[7]);
}

extern "C" void kernel_launch(void* const* d_in, const int* in_sizes, int n_in,
                              void* d_out, int out_size, void* d_ws, size_t ws_size,
                              hipStream_t stream) {
    const float* inputs   = (const float*)d_in[0];
    const float* weights  = (const float*)d_in[1];
    const float* scalings = (const float*)d_in[2];
    float* out = (float*)d_out;
    const int B = in_sizes[0] / F;                  // 131072
    const int total = B * 4;                        // 4 threads / element
    const int grid = (total + 255) / 256;           // 2048 blocks
    qnn_mps4_kernel<<<grid, 256, 0, stream>>>(inputs, weights, scalings, out, B);
}

// Round 4
// 68.149 us; speedup vs baseline: 2.0345x; 1.0062x over previous
//
#include <hip/hip_runtime.h>

// QNN as a squared bond-dim-2 MPS -> symmetric bond-dim-3 transfer chain,
// factored LEFT x RIGHT around the thread's fixed measured bits.
//
// 4 threads per element (t = gtid&3 -> z0 = t>>1, z1 = t0^t1, tb = t&1).
// p(G=8t+u) = l(z0,z1,z2) . r3[(z3<<1)|z4],  z2 = (u>>2)^tb,
//   z3 = bit1(u)^bit2(u), z4 = bit0(u)^bit1(u)   (gray decode, verified vs
//   the passing round-2/3 kernels).
// Left: l0 = row0 of E0(z0); l1 = l0.E1(z1); lA = l1.E2(tb), lB = l1.E2(!tb)
//   -> 8 outputs are 8 dot-3s (was 8 full 3x3 matvecs + dots).
// Right: r5 = (1, sin theta1_5, 1) after tracing qubits 5,6,7;
//   r4[2] = E4(z4).r5 ; r3[4] = E3(z3).r4.
// Per-thread ~260 VALU (was ~500); live set ~40 regs; __launch_bounds__(256,8)
// pins <=64 VGPR -> 8 waves/SIMD for latency hiding.

constexpr int F = 16;

struct Sym { float P, Q, R; };
struct Ent { float up, uq, ur, vp, vq, vr, t, tr2; };
struct Eff { float A, B, C, D, E, Fc, G, H; };   // [[A,B,C],[D,E,F],[G,B,H]]

__device__ __forceinline__ Ent mk_ent(float c1, float s1, float c2, float s2) {
    const float u = c2 * c2, v = s2 * s2, t = c2 * s2;
    const float p = c1 * c1, q = s1 * s1, r = c1 * s1;
    Ent e;
    e.up = u * p; e.uq = u * q; e.ur = u * r;
    e.vp = v * p; e.vq = v * q; e.vr = v * r;
    e.t  = t;     e.tr2 = 2.0f * t * r;
    return e;
}

// V' = T(z) V :
// z=0: P'=up P -tr2 Q +vq R ; Q'=ur P -t Q +vr R ; R'=uq P -tr2 Q +vp R
// z=1: P'=vp P +tr2 Q +uq R ; Q'=vr P +t Q +ur R ; R'=vq P +tr2 Q +up R
template <int Z>
__device__ __forceinline__ Sym apply_z(const Ent& e, const Sym& s) {
    if (Z == 0) {
        return Sym{ fmaf(e.up, s.P, fmaf(-e.tr2, s.Q, e.vq * s.R)),
                    fmaf(e.ur, s.P, fmaf(-e.t,   s.Q, e.vr * s.R)),
                    fmaf(e.uq, s.P, fmaf(-e.tr2, s.Q, e.vp * s.R)) };
    } else {
        return Sym{ fmaf(e.vp, s.P, fmaf( e.tr2, s.Q, e.uq * s.R)),
                    fmaf(e.vr, s.P, fmaf( e.t,   s.Q, e.ur * s.R)),
                    fmaf(e.vq, s.P, fmaf( e.tr2, s.Q, e.up * s.R)) };
    }
}

__device__ __forceinline__ Eff mk_eff(const Ent& e, bool z) {
    Eff f;
    f.A = z ? e.vp  :  e.up;   f.B = z ? e.tr2 : -e.tr2;
    f.C = z ? e.uq  :  e.vq;   f.D = z ? e.vr  :  e.ur;
    f.E = z ? e.t   : -e.t;    f.Fc= z ? e.ur  :  e.vr;
    f.G = z ? e.vq  :  e.uq;   f.H = z ? e.up  :  e.vp;
    return f;
}
// opposite-z variant: permutation + sign flips
__device__ __forceinline__ Eff flip_eff(const Eff& e) {
    return Eff{ e.H, -e.B, e.G, e.Fc, -e.E, e.D, e.C, e.A };
}
// row-vector times matrix: l' = l^T M  (col1 of M is (B,E,B))
__device__ __forceinline__ Sym lmul(const Sym& l, const Eff& e) {
    return Sym{ fmaf(e.A, l.P, fmaf(e.D, l.Q, e.G * l.R)),
                fmaf(e.B, l.P + l.R, e.E * l.Q),
                fmaf(e.C, l.P, fmaf(e.Fc, l.Q, e.H * l.R)) };
}

__global__ __launch_bounds__(256, 8) void qnn_lr_kernel(
    const float* __restrict__ inputs,
    const float* __restrict__ weights,
    const float* __restrict__ scalings,
    float* __restrict__ out, int B)
{
    const int g = blockIdx.x * 256 + threadIdx.x;
    const int b = g >> 2;
    const int t = g & 3;
    if (b >= B) return;

    const bool z0 = (t >> 1) & 1;
    const bool z1 = ((t ^ (t >> 1)) & 1);
    const bool tb = (t & 1);

    // ---- features actually used: x0..x5 (layer1 w0..5), x8..x12 (layer2 w0..4)
    const float4* in4 = reinterpret_cast<const float4*>(inputs) + (size_t)b * 4;
    const float4 xa = in4[0], xb = in4[1], xc = in4[2];
    const float x12 = inputs[(size_t)b * F + 12];

    const float xs1[5] = { xa.x, xa.y, xa.z, xa.w, xb.x };
    const float xs2[5] = { xc.x, xc.y, xc.z, xc.w, x12 };

    float c1[5], s1[5], c2[5], s2[5];
    #pragma unroll
    for (int w = 0; w < 5; ++w) {
        const float t1 = weights[w]     + scalings[w]     * xs1[w];
        const float t2 = weights[8 + w] + scalings[8 + w] * xs2[w];
        __sincosf(0.5f * t1, &s1[w], &c1[w]);
        __sincosf(0.5f * t2, &s2[w], &c2[w]);
    }
    const float th5 = weights[5] + scalings[5] * xb.y;
    const float s5  = __sinf(th5);

    // ---- right tree: qubits 4,3 over r5 = (1, s5, 1)
    const Sym r5{ 1.0f, s5, 1.0f };
    const Ent e4 = mk_ent(c1[4], s1[4], c2[4], s2[4]);
    Sym r4[2];
    r4[0] = apply_z<0>(e4, r5);
    r4[1] = apply_z<1>(e4, r5);

    const Ent e3 = mk_ent(c1[3], s1[3], c2[3], s2[3]);
    Sym r3[4];                              // index = (z3<<1)|z4
    r3[0] = apply_z<0>(e3, r4[0]);  r3[1] = apply_z<0>(e3, r4[1]);
    r3[2] = apply_z<1>(e3, r4[0]);  r3[3] = apply_z<1>(e3, r4[1]);

    // ---- left chain: qubits 0,1,2 (thread-fixed bits)
    const Ent e0 = mk_ent(c1[0], s1[0], c2[0], s2[0]);
    const Sym l0{ z0 ? e0.vp  :  e0.up,
                  z0 ? e0.tr2 : -e0.tr2,
                  z0 ? e0.uq  :  e0.vq };            // row 0 of E0(z0)
    const Eff e1e = mk_eff(mk_ent(c1[1], s1[1], c2[1], s2[1]), z1);
    const Sym l1 = lmul(l0, e1e);
    const Eff e2a = mk_eff(mk_ent(c1[2], s1[2], c2[2], s2[2]), tb);
    const Eff e2b = flip_eff(e2a);
    const Sym lA = lmul(l1, e2a);           // z2 == tb  (u bit2 == 0)
    const Sym lB = lmul(l1, e2b);           // z2 == !tb (u bit2 == 1)

    // ---- 8 outputs = 8 dot-3s (all indices compile-time)
    float pr[8];
    #pragma unroll
    for (int u = 0; u < 8; ++u) {
        const int u2 = (u >> 2) & 1;
        const int z3 = ((u >> 1) ^ (u >> 2)) & 1;
        const int z4 = (u ^ (u >> 1)) & 1;
        const Sym& l = u2 ? lB : lA;
        const Sym& r = r3[(z3 << 1) | z4];
        pr[u] = fmaf(l.P, r.P, fmaf(l.Q, r.Q, l.R * r.R));
    }

    float4* o4 = reinterpret_cast<float4*>(out) + (size_t)b * 8 + (size_t)t * 2;
    o4[0] = make_float4(pr[0], pr[1], pr[2], pr[3]);
    o4[1] = make_float4(pr[4], pr[5], pr[6], pr[7]);
}

extern "C" void kernel_launch(void* const* d_in, const int* in_sizes, int n_in,
                              void* d_out, int out_size, void* d_ws, size_t ws_size,
                              hipStream_t stream) {
    const float* inputs   = (const float*)d_in[0];
    const float* weights  = (const float*)d_in[1];
    const float* scalings = (const float*)d_in[2];
    float* out = (float*)d_out;
    const int B = in_sizes[0] / F;                  // 131072
    const int total = B * 4;                        // 4 threads / element
    const int grid = (total + 255) / 256;           // 2048 blocks
    qnn_lr_kernel<<<grid, 256, 0, stream>>>(inputs, weights, scalings, out, B);
}